// Round 1
// baseline (500.345 us; speedup 1.0000x reference)
//
#include <hip/hip_runtime.h>
#include <math.h>

#define DIM 394
#define BN_EPS 1e-5f

// ---------------------------------------------------------------------------
// ws layout (floats): deg/dinv [N] | y [2N] | fcwT [DIM*DIM] | flag (1 int)
// ---------------------------------------------------------------------------

__global__ void init_kernel(float* deg, float* y, int* flag, int n) {
    int v = blockIdx.x * blockDim.x + threadIdx.x;
    if (v < n) {
        deg[v] = 1.0f;          // self-loop
        y[2 * v] = 0.0f;
        y[2 * v + 1] = 0.0f;
    }
    if (v == 0) *flag = 0;
}

// Detect whether edge_index is int32 or int64.
// Reads the first 2*e int32 words (safe for both layouts). If the buffer is
// int64 (little-endian, values < 50000 >= 0), every odd word is 0.
// If int32, odd words are random node indices -> OR is nonzero.
__global__ void detect_kernel(const int* ei, int e, int* flag) {
    int i = blockIdx.x * blockDim.x + threadIdx.x;
    int stride = gridDim.x * blockDim.x;
    int acc = 0;
    for (int j = i; j < e; j += stride) acc |= ei[2 * j + 1];
    if (acc != 0) *flag = 1;   // all writers write the same value
}

__global__ void deg_kernel(const int* ei, float* deg, int e, const int* flag) {
    int i = blockIdx.x * blockDim.x + threadIdx.x;
    if (i >= e) return;
    int d;
    if (*flag) d = ei[e + i];            // int32: dst row at word offset e
    else       d = ei[2 * (e + i)];      // int64: low word of element e+i
    atomicAdd(&deg[d], 1.0f);
}

__global__ void dinv_kernel(float* deg, int n) {
    int v = blockIdx.x * blockDim.x + threadIdx.x;
    if (v < n) deg[v] = rsqrtf(deg[v]);  // deg >= 1 always (self-loop)
}

__global__ void scatter_kernel(const int* ei, const float* __restrict__ x,
                               const float* __restrict__ dinv, float* y,
                               int e, const int* flag) {
    int i = blockIdx.x * blockDim.x + threadIdx.x;
    if (i >= e) return;
    int s, d;
    if (*flag) { s = ei[i];     d = ei[e + i]; }
    else       { s = ei[2 * i]; d = ei[2 * (e + i)]; }
    float nrm = dinv[s] * dinv[d];
    atomicAdd(&y[2 * d],     x[2 * s]     * nrm);
    atomicAdd(&y[2 * d + 1], x[2 * s + 1] * nrm);
}

// fcwT[k][j] = fc_w[j][k]  (so GEMM B-tile staging is coalesced + conflict-free)
__global__ void transpose_kernel(const float* __restrict__ fcw,
                                 float* __restrict__ fcwT) {
    __shared__ float tile[32][33];
    int bx = blockIdx.x * 32, by = blockIdx.y * 32;
    int tx = threadIdx.x, ty = threadIdx.y;   // block (32, 8)
    for (int r = ty; r < 32; r += 8) {
        int row = by + r, col = bx + tx;
        tile[r][tx] = (row < DIM && col < DIM) ? fcw[row * DIM + col] : 0.0f;
    }
    __syncthreads();
    for (int r = ty; r < 32; r += 8) {
        int row = bx + r, col = by + tx;
        if (row < DIM && col < DIM) fcwT[row * DIM + col] = tile[tx][r];
    }
}

// ---------------------------------------------------------------------------
// Fused GEMM: z[i][j] = sum_k h[i][k] * fc_w[j][k] + fc_b[j]
// where h[i][k] = BN(relu(y_tot[i] . W_gcn[k] + b_gcn[k])) is computed
// on-the-fly during A-tile staging (h is never materialized).
// y_tot[i] = y_scatter[i] + x[i] * dinv[i]^2   (self-loop term)
// Tile: BM=64, BN=64, BK=16, 256 threads, 4x4 microtile per thread.
// ---------------------------------------------------------------------------
#define TBM 64
#define TBN 64
#define TBK 16

__global__ __launch_bounds__(256)
void gemm_kernel(const float* __restrict__ x, const float* __restrict__ dinv,
                 const float* __restrict__ y,
                 const float* __restrict__ Wg, const float* __restrict__ bg,
                 const float* __restrict__ gamma, const float* __restrict__ beta,
                 const float* __restrict__ mean, const float* __restrict__ var,
                 const float* __restrict__ fcwT, const float* __restrict__ fcb,
                 float* __restrict__ z, int n) {
    __shared__ float As[TBK][TBM];   // As[k][m]
    __shared__ float Bs[TBK][TBN];   // Bs[k][j]

    int tid = threadIdx.x;
    int row0 = blockIdx.x * TBM;
    int col0 = blockIdx.y * TBN;
    int tx = tid & 15, ty = tid >> 4;     // 16x16 thread grid

    // hoisted per-row values for A staging (this thread always stages row m)
    int m = tid & 63;
    int i = row0 + m;
    float y0 = 0.0f, y1 = 0.0f;
    bool irow = (i < n);
    if (irow) {
        float di = dinv[i];
        float d2 = di * di;
        y0 = y[2 * i]     + x[2 * i]     * d2;
        y1 = y[2 * i + 1] + x[2 * i + 1] * d2;
    }
    int kbase = tid >> 6;  // 0..3

    float acc[4][4] = {};

    for (int k0 = 0; k0 < DIM; k0 += TBK) {
        // stage A (compute h on the fly): 64 rows x 16 k, 4 k's per thread
        #pragma unroll
        for (int q = 0; q < 4; ++q) {
            int kk = kbase + q * 4;
            int k = k0 + kk;
            float a = 0.0f;
            if (irow && k < DIM) {
                float t0 = fmaf(y0, Wg[2 * k], fmaf(y1, Wg[2 * k + 1], bg[k]));
                t0 = fmaxf(t0, 0.0f);
                float s = gamma[k] * rsqrtf(var[k] + BN_EPS);
                a = (t0 - mean[k]) * s + beta[k];
            }
            As[kk][m] = a;
        }
        // stage B from transposed weights: coalesced, conflict-free
        #pragma unroll
        for (int q = 0; q < 4; ++q) {
            int kk = kbase + q * 4;
            int k = k0 + kk;
            int j = col0 + m;
            Bs[kk][m] = (k < DIM && j < DIM) ? fcwT[k * DIM + j] : 0.0f;
        }
        __syncthreads();

        #pragma unroll
        for (int kk = 0; kk < TBK; ++kk) {
            float4 av = *reinterpret_cast<const float4*>(&As[kk][ty * 4]);
            float4 bv = *reinterpret_cast<const float4*>(&Bs[kk][tx * 4]);
            float a4[4] = {av.x, av.y, av.z, av.w};
            float b4[4] = {bv.x, bv.y, bv.z, bv.w};
            #pragma unroll
            for (int u = 0; u < 4; ++u)
                #pragma unroll
                for (int v = 0; v < 4; ++v)
                    acc[u][v] = fmaf(a4[u], b4[v], acc[u][v]);
        }
        __syncthreads();
    }

    // epilogue: z = acc + fcb
    #pragma unroll
    for (int u = 0; u < 4; ++u) {
        int r = row0 + ty * 4 + u;
        if (r >= n) continue;
        #pragma unroll
        for (int v = 0; v < 4; ++v) {
            int c = col0 + tx * 4 + v;
            if (c < DIM) z[(size_t)r * DIM + c] = acc[u][v] + fcb[c];
        }
    }
}

// ---------------------------------------------------------------------------
// log_softmax per row: out = z - max - log(sum(exp(z - max)))
// one block (256 threads) per row; each thread owns <= 2 elements.
// ---------------------------------------------------------------------------
__global__ __launch_bounds__(256)
void lsm_kernel(const float* __restrict__ z, float* __restrict__ out, int n) {
    int row = blockIdx.x;
    const float* zr = z + (size_t)row * DIM;
    int tid = threadIdx.x;

    float v0 = (tid < DIM)       ? zr[tid]       : -INFINITY;
    float v1 = (tid + 256 < DIM) ? zr[tid + 256] : -INFINITY;

    float mx = fmaxf(v0, v1);
    #pragma unroll
    for (int o = 32; o > 0; o >>= 1) mx = fmaxf(mx, __shfl_xor(mx, o));
    __shared__ float sm[4];
    int wid = tid >> 6, lane = tid & 63;
    if (lane == 0) sm[wid] = mx;
    __syncthreads();
    mx = fmaxf(fmaxf(sm[0], sm[1]), fmaxf(sm[2], sm[3]));

    float s = 0.0f;
    if (tid < DIM)       s += expf(v0 - mx);
    if (tid + 256 < DIM) s += expf(v1 - mx);
    #pragma unroll
    for (int o = 32; o > 0; o >>= 1) s += __shfl_xor(s, o);
    __shared__ float ss[4];
    if (lane == 0) ss[wid] = s;
    __syncthreads();
    s = ss[0] + ss[1] + ss[2] + ss[3];

    float lse = mx + logf(s);
    float* outr = out + (size_t)row * DIM;
    if (tid < DIM)       outr[tid]       = v0 - lse;
    if (tid + 256 < DIM) outr[tid + 256] = v1 - lse;
}

// ---------------------------------------------------------------------------
extern "C" void kernel_launch(void* const* d_in, const int* in_sizes, int n_in,
                              void* d_out, int out_size, void* d_ws, size_t ws_size,
                              hipStream_t stream) {
    int n = in_sizes[0] / 2;       // 50000 nodes
    int e = in_sizes[1] / 2;       // 800000 edges

    const float* x     = (const float*)d_in[0];
    const int*   ei    = (const int*)d_in[1];
    const float* Wg    = (const float*)d_in[2];
    const float* bg    = (const float*)d_in[3];
    const float* gamma = (const float*)d_in[4];
    const float* beta  = (const float*)d_in[5];
    const float* mean  = (const float*)d_in[6];
    const float* var   = (const float*)d_in[7];
    const float* fcw   = (const float*)d_in[8];
    const float* fcb   = (const float*)d_in[9];

    float* out = (float*)d_out;                 // [n, DIM] log_softmax
    float* z   = out + (size_t)n * DIM;         // [n, DIM] logits

    float* deg  = (float*)d_ws;                 // n floats (becomes dinv)
    float* y    = deg + n;                      // 2n floats
    float* fcwT = y + 2 * (size_t)n;            // DIM*DIM floats
    int*   flag = (int*)(fcwT + (size_t)DIM * DIM);

    int nb = (n + 255) / 256;
    int ebk = (e + 255) / 256;

    init_kernel<<<nb, 256, 0, stream>>>(deg, y, flag, n);
    detect_kernel<<<256, 256, 0, stream>>>(ei, e, flag);
    deg_kernel<<<ebk, 256, 0, stream>>>(ei, deg, e, flag);
    dinv_kernel<<<nb, 256, 0, stream>>>(deg, n);
    scatter_kernel<<<ebk, 256, 0, stream>>>(ei, x, deg, y, e, flag);

    dim3 tg((DIM + 31) / 32, (DIM + 31) / 32);
    transpose_kernel<<<tg, dim3(32, 8), 0, stream>>>(fcw, fcwT);

    dim3 gg((n + TBM - 1) / TBM, (DIM + TBN - 1) / TBN);
    gemm_kernel<<<gg, 256, 0, stream>>>(x, deg, y, Wg, bg, gamma, beta,
                                        mean, var, fcwT, fcb, z, n);

    lsm_kernel<<<n, 256, 0, stream>>>(z, out, n);
}

// Round 2
// 231.052 us; speedup vs baseline: 2.1655x; 2.1655x over previous
//
#include <hip/hip_runtime.h>
#include <math.h>

#define DIM 394
#define KP  416      // padded K = 13*32
#define NT  13       // K-steps
#define NP  448      // padded N = 28*16
#define BN_EPS 1e-5f

typedef __bf16 bf16x8 __attribute__((ext_vector_type(8)));
typedef float  f32x4  __attribute__((ext_vector_type(4)));

__device__ inline void gload_lds16(const void* g, void* l) {
    __builtin_amdgcn_global_load_lds(
        (const __attribute__((address_space(1))) void*)g,
        (__attribute__((address_space(3))) void*)l, 16, 0, 0);
}

// ---------------------------------------------------------------------------
// ws layout: deg[n] | y[2n] | (align 256) Bp[13*4*448 bf16x8] | Pk[KP float4]
//            | Ok[KP float] | flag
// ---------------------------------------------------------------------------

__global__ void init_kernel(float* deg, float* y, int* flag, int n) {
    int v = blockIdx.x * blockDim.x + threadIdx.x;
    if (v < n) {
        deg[v] = 1.0f;          // self-loop
        y[2 * v] = 0.0f;
        y[2 * v + 1] = 0.0f;
    }
    if (v == 0) *flag = 0;
}

// int32 vs int64 edge_index probe (odd words all zero <=> int64)
__global__ void detect_kernel(const int* ei, int e, int* flag) {
    int i = blockIdx.x * blockDim.x + threadIdx.x;
    int stride = gridDim.x * blockDim.x;
    int acc = 0;
    for (int j = i; j < e; j += stride) acc |= ei[2 * j + 1];
    if (acc != 0) *flag = 1;
}

__global__ void deg_kernel(const int* ei, float* deg, int e, const int* flag) {
    int i = blockIdx.x * blockDim.x + threadIdx.x;
    if (i >= e) return;
    int d;
    if (*flag) d = ei[e + i];
    else       d = ei[2 * (e + i)];
    atomicAdd(&deg[d], 1.0f);
}

__global__ void dinv_kernel(float* deg, int n) {
    int v = blockIdx.x * blockDim.x + threadIdx.x;
    if (v < n) deg[v] = rsqrtf(deg[v]);
}

__global__ void scatter_kernel(const int* ei, const float* __restrict__ x,
                               const float* __restrict__ dinv, float* y,
                               int e, const int* flag) {
    int i = blockIdx.x * blockDim.x + threadIdx.x;
    if (i >= e) return;
    int s, d;
    if (*flag) { s = ei[i];     d = ei[e + i]; }
    else       { s = ei[2 * i]; d = ei[2 * (e + i)]; }
    float nrm = dinv[s] * dinv[d];
    atomicAdd(&y[2 * d],     x[2 * s]     * nrm);
    atomicAdd(&y[2 * d + 1], x[2 * s + 1] * nrm);
}

// per-k GCN+BN constants: Pk = {w0, w1, bg, s}, Ok = beta - s*mean
__global__ void pk_kernel(const float* __restrict__ Wg, const float* __restrict__ bg,
                          const float* __restrict__ gamma, const float* __restrict__ beta,
                          const float* __restrict__ mean, const float* __restrict__ var,
                          float4* __restrict__ Pk, float* __restrict__ Ok) {
    int k = blockIdx.x * blockDim.x + threadIdx.x;
    if (k >= KP) return;
    float4 p = make_float4(0.f, 0.f, 0.f, 0.f);
    float o = 0.f;
    if (k < DIM) {
        p.x = Wg[2 * k];
        p.y = Wg[2 * k + 1];
        p.z = bg[k];
        float s = gamma[k] * rsqrtf(var[k] + BN_EPS);
        p.w = s;
        o = beta[k] - s * mean[k];
    }
    Pk[k] = p;
    Ok[k] = o;
}

// B = fc_w^T packed bf16 in MFMA fragment order: Bp[(ks*4+kc)*448 + col][q=k%8]
__global__ void bprep_kernel(const float* __restrict__ fcw, bf16x8* __restrict__ Bp) {
    int idx = blockIdx.x * blockDim.x + threadIdx.x;
    if (idx >= NT * 4 * NP) return;
    int col = idx % NP;
    int r   = idx / NP;      // ks*4 + kc
    int k0  = r * 8;         // = ks*32 + kc*8
    bf16x8 v;
    #pragma unroll
    for (int q = 0; q < 8; ++q) {
        int k = k0 + q;
        float f = (col < DIM && k < DIM) ? fcw[col * DIM + k] : 0.0f;
        v[q] = (__bf16)f;
    }
    Bp[idx] = v;
}

// ---------------------------------------------------------------------------
// Fused: h = BN(relu(GCN)) on-the-fly -> bf16 MFMA GEMM vs fc_w^T -> +fc_b
//        -> z store + log_softmax store. Block: 256 thr / 4 waves.
// BM=64 rows, BN=448 cols (wave w owns cols [w*112, w*112+112)), K=416.
// ---------------------------------------------------------------------------
__global__ __launch_bounds__(256, 2)
void gemm_fused(const float* __restrict__ x, const float* __restrict__ dinv,
                const float* __restrict__ y,
                const float4* __restrict__ Pk, const float* __restrict__ Ok,
                const bf16x8* __restrict__ Bp, const float* __restrict__ fcb,
                float* __restrict__ outp, float* __restrict__ z, int n) {
    __shared__ bf16x8 As[2][256];    // [kc(4)][row(64)] per buffer, 4KB each
    __shared__ bf16x8 Bs[2][1792];   // [kc(4)][col(448)] per buffer, 28KB each

    int tid = threadIdx.x;
    int wv  = tid >> 6;          // wave id (= kc for A staging, col group)
    int l   = tid & 63;
    int cg  = l & 15;            // col/row within 16-tile
    int kg  = l >> 4;            // k-group (8 k's each)
    int row0 = blockIdx.x * 64;

    // per-thread A-staging row (row l of the block tile)
    int gi = row0 + l;
    float y0 = 0.f, y1 = 0.f;
    if (gi < n) {
        float di = dinv[gi], d2 = di * di;
        y0 = y[2 * gi]     + x[2 * gi]     * d2;
        y1 = y[2 * gi + 1] + x[2 * gi + 1] * d2;
    }

    f32x4 acc[4][7];
    #pragma unroll
    for (int a = 0; a < 4; ++a)
        #pragma unroll
        for (int b = 0; b < 7; ++b)
            acc[a][b] = (f32x4){0.f, 0.f, 0.f, 0.f};

    auto stageA = [&](int ks, int buf) {
        int kb = ks * 32 + wv * 8;
        bf16x8 hv;
        #pragma unroll
        for (int q = 0; q < 8; ++q) {
            float4 p = Pk[kb + q];
            float t = fmaf(y0, p.x, fmaf(y1, p.y, p.z));
            t = fmaxf(t, 0.f);
            hv[q] = (__bf16)fmaf(p.w, t, Ok[kb + q]);
        }
        As[buf][wv * 64 + l] = hv;
    };
    auto stageB = [&](int ks, int buf) {
        const char* g = (const char*)Bp + (size_t)ks * 28672 + (size_t)l * 16;
        char* lb = (char*)&Bs[buf][0];
        #pragma unroll
        for (int c = 0; c < 7; ++c) {
            int off = (wv * 7 + c) * 1024;
            gload_lds16(g + off, lb + off);
        }
    };
    auto compute = [&](int buf) {
        bf16x8 af[4];
        #pragma unroll
        for (int rt = 0; rt < 4; ++rt)
            af[rt] = As[buf][kg * 64 + rt * 16 + cg];
        #pragma unroll
        for (int ct = 0; ct < 7; ++ct) {
            bf16x8 bfr = Bs[buf][kg * 448 + wv * 112 + ct * 16 + cg];
            #pragma unroll
            for (int rt = 0; rt < 4; ++rt)
                acc[rt][ct] = __builtin_amdgcn_mfma_f32_16x16x32_bf16(
                                  af[rt], bfr, acc[rt][ct], 0, 0, 0);
        }
    };

    stageB(0, 0);
    stageA(0, 0);
    __syncthreads();
    int buf = 0;
    for (int ks = 0; ks < NT; ++ks) {
        if (ks < NT - 1) { stageB(ks + 1, buf ^ 1); stageA(ks + 1, buf ^ 1); }
        compute(buf);
        __syncthreads();
        buf ^= 1;
    }

    // ---------------- epilogue: bias + log_softmax + stores ----------------
    float* redm = (float*)&As[0][0];   // 64 rows x 4 waves (As dead now)
    float* reds = redm + 256;

    int colb = wv * 112;
    float bias[7];
    bool  cv[7];
    #pragma unroll
    for (int ct = 0; ct < 7; ++ct) {
        int c = colb + ct * 16 + cg;
        cv[ct] = (c < DIM);
        bias[ct] = cv[ct] ? fcb[c] : 0.f;
    }
    #pragma unroll
    for (int rt = 0; rt < 4; ++rt)
        #pragma unroll
        for (int ct = 0; ct < 7; ++ct)
            acc[rt][ct] = acc[rt][ct] + bias[ct];

    // row max over this wave's cols
    f32x4 mx[4];
    #pragma unroll
    for (int rt = 0; rt < 4; ++rt) {
        f32x4 m = (f32x4){-1e30f, -1e30f, -1e30f, -1e30f};
        #pragma unroll
        for (int ct = 0; ct < 7; ++ct) {
            if (!cv[ct]) continue;
            #pragma unroll
            for (int j = 0; j < 4; ++j) m[j] = fmaxf(m[j], acc[rt][ct][j]);
        }
        #pragma unroll
        for (int msk = 1; msk < 16; msk <<= 1)
            #pragma unroll
            for (int j = 0; j < 4; ++j)
                m[j] = fmaxf(m[j], __shfl_xor(m[j], msk));
        mx[rt] = m;
    }
    if (cg == 0) {
        #pragma unroll
        for (int rt = 0; rt < 4; ++rt)
            #pragma unroll
            for (int j = 0; j < 4; ++j)
                redm[(rt * 16 + kg * 4 + j) * 4 + wv] = mx[rt][j];
    }
    __syncthreads();
    f32x4 gm[4];
    #pragma unroll
    for (int rt = 0; rt < 4; ++rt)
        #pragma unroll
        for (int j = 0; j < 4; ++j) {
            int r = (rt * 16 + kg * 4 + j) * 4;
            gm[rt][j] = fmaxf(fmaxf(redm[r], redm[r + 1]),
                              fmaxf(redm[r + 2], redm[r + 3]));
        }

    // exp-sum
    f32x4 sm[4];
    #pragma unroll
    for (int rt = 0; rt < 4; ++rt) {
        f32x4 s = (f32x4){0.f, 0.f, 0.f, 0.f};
        #pragma unroll
        for (int ct = 0; ct < 7; ++ct) {
            if (!cv[ct]) continue;
            #pragma unroll
            for (int j = 0; j < 4; ++j)
                s[j] += expf(acc[rt][ct][j] - gm[rt][j]);
        }
        #pragma unroll
        for (int msk = 1; msk < 16; msk <<= 1)
            #pragma unroll
            for (int j = 0; j < 4; ++j)
                s[j] += __shfl_xor(s[j], msk);
        sm[rt] = s;
    }
    if (cg == 0) {
        #pragma unroll
        for (int rt = 0; rt < 4; ++rt)
            #pragma unroll
            for (int j = 0; j < 4; ++j)
                reds[(rt * 16 + kg * 4 + j) * 4 + wv] = sm[rt][j];
    }
    __syncthreads();
    f32x4 lse[4];
    #pragma unroll
    for (int rt = 0; rt < 4; ++rt)
        #pragma unroll
        for (int j = 0; j < 4; ++j) {
            int r = (rt * 16 + kg * 4 + j) * 4;
            float t = reds[r] + reds[r + 1] + reds[r + 2] + reds[r + 3];
            lse[rt][j] = gm[rt][j] + logf(t);
        }

    // stores: z and out
    #pragma unroll
    for (int rt = 0; rt < 4; ++rt)
        #pragma unroll
        for (int j = 0; j < 4; ++j) {
            int grow = row0 + rt * 16 + kg * 4 + j;
            if (grow >= n) continue;
            size_t base = (size_t)grow * DIM;
            float L = lse[rt][j];
            #pragma unroll
            for (int ct = 0; ct < 7; ++ct) {
                if (!cv[ct]) continue;
                int c = colb + ct * 16 + cg;
                float zv = acc[rt][ct][j];
                z[base + c]    = zv;
                outp[base + c] = zv - L;
            }
        }
}

// ---------------------------------------------------------------------------
extern "C" void kernel_launch(void* const* d_in, const int* in_sizes, int n_in,
                              void* d_out, int out_size, void* d_ws, size_t ws_size,
                              hipStream_t stream) {
    int n = in_sizes[0] / 2;       // 50000 nodes
    int e = in_sizes[1] / 2;       // 800000 edges

    const float* x     = (const float*)d_in[0];
    const int*   ei    = (const int*)d_in[1];
    const float* Wg    = (const float*)d_in[2];
    const float* bg    = (const float*)d_in[3];
    const float* gamma = (const float*)d_in[4];
    const float* beta  = (const float*)d_in[5];
    const float* mean  = (const float*)d_in[6];
    const float* var   = (const float*)d_in[7];
    const float* fcw   = (const float*)d_in[8];
    const float* fcb   = (const float*)d_in[9];

    float* out = (float*)d_out;                 // [n, DIM] log_softmax
    float* z   = out + (size_t)n * DIM;         // [n, DIM] logits

    char* wsb = (char*)d_ws;
    float* deg = (float*)wsb;                           // n
    float* y   = deg + n;                               // 2n
    size_t off = ((size_t)(3 * n) * 4 + 255) & ~(size_t)255;
    bf16x8* Bp = (bf16x8*)(wsb + off);                  // 13*4*448 * 16B
    off += (size_t)NT * 4 * NP * 16;
    float4* Pk = (float4*)(wsb + off);                  // KP * 16B
    off += (size_t)KP * 16;
    float* Ok  = (float*)(wsb + off);                   // KP * 4B
    off += (size_t)KP * 4;
    int* flag  = (int*)(wsb + off);

    int nb  = (n + 255) / 256;
    int ebk = (e + 255) / 256;

    init_kernel<<<nb, 256, 0, stream>>>(deg, y, flag, n);
    detect_kernel<<<256, 256, 0, stream>>>(ei, e, flag);
    deg_kernel<<<ebk, 256, 0, stream>>>(ei, deg, e, flag);
    dinv_kernel<<<nb, 256, 0, stream>>>(deg, n);
    scatter_kernel<<<ebk, 256, 0, stream>>>(ei, x, deg, y, e, flag);

    pk_kernel<<<(KP + 255) / 256, 256, 0, stream>>>(Wg, bg, gamma, beta, mean, var, Pk, Ok);
    bprep_kernel<<<(NT * 4 * NP + 255) / 256, 256, 0, stream>>>(fcw, Bp);

    int gm = (n + 63) / 64;
    gemm_fused<<<gm, 256, 0, stream>>>(x, deg, y, Pk, Ok, Bp, fcb, out, z, n);
}